// Round 2
// 191.106 us; speedup vs baseline: 1.0042x; 1.0042x over previous
//
#include <hip/hip_runtime.h>

typedef __attribute__((ext_vector_type(8))) short short8;
typedef __attribute__((ext_vector_type(4))) float float4_t;
typedef __attribute__((ext_vector_type(4))) int int4_t;

#define CH_STRIDE 4096        // 64*64 spatial per channel
#define IMG_STRIDE 524288     // 128 channels * 4096
#define HW 4096
#define V520 520              // Vt row stride (shorts); 1040B rows keep 16B align

// float -> bf16 bits, round-to-nearest-even (finite inputs only)
static __device__ __forceinline__ short f2b(float x) {
    unsigned u = __builtin_bit_cast(unsigned, x);
    u = (u + 0x7fffu + ((u >> 16) & 1u)) >> 16;
    return (short)u;
}
static __device__ __forceinline__ float bitsf(unsigned u) { return __builtin_bit_cast(float, u); }
static __device__ __forceinline__ unsigned bitsu(float f) { return __builtin_bit_cast(unsigned, f); }

// Fused CSWin block: flash attention (S^T = K*Q^T, shfl P-exchange, O^T = V^T*P^T)
// + depthwise 3x3 conv rpe from the LDS-resident V, all in one launch.
// Grid 512 = (nw, b, head), nw in high bits for XCD L2 locality.
//
// R2 changes vs the 191.6us baseline (R1's half-split + (512,6) cap REVERTED:
// pow2 VGPR granule (m69: steps at 64/128/256) means an 85-reg cap buys no
// occupancy and the forced pressure spilled -> slow + replay-divergent):
//  1. Kc double-buffered -> ONE barrier per chunk instead of two. Writes for
//     chunk ch+1 go to Kc[(ch+1)&1] while waves read Kc[ch&1]; Vt regions are
//     append-only per chunk. Next-chunk global loads issue BEFORE the barrier
//     and are consumed by the LDS-write AFTER compute -> a full compute phase
//     of latency hiding.
//  2. Loader remapped key-strided (thread handles keys seg+16i, not 4seg+i):
//     Kc b16-store lane stride 80B = 20 dw (mod 32) spreads 16 segs over 8
//     banks (~2-way, free) instead of 80dw = 16 (mod 32) -> 8-way. This was
//     7.08M conflict cycles (~14% of CU-cycles). MFMA-side layout untouched.
// NOTE: plain __launch_bounds__(512) — no min-waves arg (see R1/R3 failures).
__global__ __launch_bounds__(512) void cswin_fused(
    const float* __restrict__ temp, const float* __restrict__ cw,
    const float* __restrict__ cb, float* __restrict__ out)
{
    __shared__ short Kc[2][64 * 40];   // [buf][key][d] pad-40, double-buffered
    __shared__ short Vt[32 * V520];    // [d][l] full 512-key window, persistent

    int bx = blockIdx.x;
    int nw = bx >> 6;          // window column 0..7
    int r  = bx & 63;
    int b  = r >> 2;           // batch 0..15
    int n  = r & 3;            // head 0..3

    int t    = threadIdx.x;
    int wv   = t >> 6;         // wave 0..7
    int lane = t & 63;
    int mr   = lane & 15;
    int q    = lane >> 4;

    const float* tq = temp + (size_t)b * 3 * IMG_STRIDE + (size_t)(n * 32) * CH_STRIDE + nw * 8;
    const float* tk = tq + IMG_STRIDE;
    const float* tv = tk + IMG_STRIDE;

    int row0 = wv * 64;        // this wave's 64 q-rows
    const float qscale = 0.2550348889072310f;   // (1/sqrt(32)) * log2(e)

    // Q fragments (B-operand): lane holds Q[row0+qt*16+mr][q*8+j] * qscale
    short8 Qf[4];
    #pragma unroll
    for (int qt = 0; qt < 4; ++qt) {
        int l = row0 + qt * 16 + mr;
        int sp = (l >> 3) * 64 + (l & 7);
        short8 f;
        #pragma unroll
        for (int j = 0; j < 8; ++j)
            f[j] = f2b(tq[(q * 8 + j) * CH_STRIDE + sp] * qscale);
        Qf[qt] = f;
    }

    float4_t zero4 = {0.f, 0.f, 0.f, 0.f};
    float4_t acc[2][4];
    #pragma unroll
    for (int dt = 0; dt < 2; ++dt)
        #pragma unroll
        for (int qt = 0; qt < 4; ++qt)
            acc[dt][qt] = zero4;
    float lsum[4] = {0.f, 0.f, 0.f, 0.f};

    // loader mapping: 512 threads = 32 d x 16 key-slots; thread (ld,seg)
    // handles keys seg+16i (i=0..3) -> conflict-free-ish b16 Kc stores.
    int ld  = t >> 4;          // channel d 0..31
    int seg = t & 15;
    const float* tkld = tk + (size_t)ld * CH_STRIDE;
    const float* tvld = tv + (size_t)ld * CH_STRIDE;

    float kx[4], vx[4];
    #pragma unroll
    for (int i = 0; i < 4; ++i) {      // prefetch chunk 0
        int lb = seg + 16 * i;
        int sp = (lb >> 3) * 64 + (lb & 7);
        kx[i] = tkld[sp]; vx[i] = tvld[sp];
    }
    {   // prologue: stage chunk 0 into Kc[0] / Vt[0..63]
        #pragma unroll
        for (int i = 0; i < 4; ++i) {
            int kl = seg + 16 * i;
            Kc[0][kl * 40 + ld] = f2b(kx[i]);
            Vt[ld * V520 + kl]  = f2b(vx[i]);
        }
    }

    int s0lane = (q & 1) * 32 + mr;    // shfl sources for the P exchange
    int s1lane = s0lane + 16;
    bool hiq = (q >= 2);

    for (int ch = 0; ch < 8; ++ch) {
        if (ch < 7) {          // issue next chunk's loads before the barrier
            #pragma unroll
            for (int i = 0; i < 4; ++i) {
                int lb = (ch + 1) * 64 + seg + 16 * i;
                int sp = (lb >> 3) * 64 + (lb & 7);
                kx[i] = tkld[sp]; vx[i] = tvld[sp];
            }
        }
        __syncthreads();       // publishes chunk ch's Kc/Vt writes
        const short* Kr = Kc[ch & 1];

        #pragma unroll
        for (int g = 0; g < 2; ++g) {
            // S^T tiles: D[m=key][n=qrow], keys g*32..g*32+31 (local to chunk)
            short8 KaA = *reinterpret_cast<const short8*>(&Kr[((2 * g) * 16 + mr) * 40 + q * 8]);
            short8 KaB = *reinterpret_cast<const short8*>(&Kr[((2 * g + 1) * 16 + mr) * 40 + q * 8]);
            unsigned pa0[4], pa1[4], pb0[4], pb1[4];
            #pragma unroll
            for (int qt = 0; qt < 4; ++qt) {
                float4_t sA = __builtin_amdgcn_mfma_f32_16x16x32_bf16(KaA, Qf[qt], zero4, 0, 0, 0);
                float4_t sB = __builtin_amdgcn_mfma_f32_16x16x32_bf16(KaB, Qf[qt], zero4, 0, 0, 0);
                float eA0 = __builtin_amdgcn_exp2f(sA.x), eA1 = __builtin_amdgcn_exp2f(sA.y);
                float eA2 = __builtin_amdgcn_exp2f(sA.z), eA3 = __builtin_amdgcn_exp2f(sA.w);
                float eB0 = __builtin_amdgcn_exp2f(sB.x), eB1 = __builtin_amdgcn_exp2f(sB.y);
                float eB2 = __builtin_amdgcn_exp2f(sB.z), eB3 = __builtin_amdgcn_exp2f(sB.w);
                lsum[qt] += ((eA0 + eA1) + (eA2 + eA3)) + ((eB0 + eB1) + (eB2 + eB3));
                // pack pairs (truncation) with one v_perm each: [lo16=e_even, hi16=e_odd]
                pa0[qt] = __builtin_amdgcn_perm(bitsu(eA1), bitsu(eA0), 0x07060302u);
                pa1[qt] = __builtin_amdgcn_perm(bitsu(eA3), bitsu(eA2), 0x07060302u);
                pb0[qt] = __builtin_amdgcn_perm(bitsu(eB1), bitsu(eB0), 0x07060302u);
                pb1[qt] = __builtin_amdgcn_perm(bitsu(eB3), bitsu(eB2), 0x07060302u);
            }
            // V^T A-fragments for this 32-key group
            int base = ch * 64 + g * 32 + q * 8;
            short8 Va0 = *reinterpret_cast<const short8*>(&Vt[mr * V520 + base]);
            short8 Va1 = *reinterpret_cast<const short8*>(&Vt[(16 + mr) * V520 + base]);
            #pragma unroll
            for (int qt = 0; qt < 4; ++qt) {
                // exchange C-layout P (keys q*4+r per quad) -> B-operand (keys q*8+j)
                int x0 = __shfl((int)pa0[qt], s0lane); int y0 = __shfl((int)pb0[qt], s0lane);
                int x1 = __shfl((int)pa1[qt], s0lane); int y1 = __shfl((int)pb1[qt], s0lane);
                int x2 = __shfl((int)pa0[qt], s1lane); int y2 = __shfl((int)pb0[qt], s1lane);
                int x3 = __shfl((int)pa1[qt], s1lane); int y3 = __shfl((int)pb1[qt], s1lane);
                int4_t pi = { hiq ? y0 : x0, hiq ? y1 : x1, hiq ? y2 : x2, hiq ? y3 : x3 };
                short8 Pb = __builtin_bit_cast(short8, pi);
                acc[0][qt] = __builtin_amdgcn_mfma_f32_16x16x32_bf16(Va0, Pb, acc[0][qt], 0, 0, 0);
                acc[1][qt] = __builtin_amdgcn_mfma_f32_16x16x32_bf16(Va1, Pb, acc[1][qt], 0, 0, 0);
            }
        }

        if (ch < 7) {          // stage chunk ch+1 (loads hidden under compute)
            short* Kw = Kc[(ch + 1) & 1];
            #pragma unroll
            for (int i = 0; i < 4; ++i) {
                int kl = seg + 16 * i;
                Kw[kl * 40 + ld] = f2b(kx[i]);
                Vt[ld * V520 + (ch + 1) * 64 + kl] = f2b(vx[i]);
            }
        }
    }

    // softmax denominators: reduce across quads, invert
    float inv[4];
    #pragma unroll
    for (int qt = 0; qt < 4; ++qt) {
        float v = lsum[qt];
        v += __shfl_xor(v, 16);
        v += __shfl_xor(v, 32);
        inv[qt] = 1.0f / v;
    }

    // O store: lane holds O[qrow=row0+qt*16+mr][c = n*32 + dt*16 + q*4 + r]
    float* outb = out + (size_t)b * HW * 128 + nw * 8 * 128 + n * 32;
    #pragma unroll
    for (int qt = 0; qt < 4; ++qt) {
        int l = row0 + qt * 16 + mr;
        size_t basep = (size_t)((l >> 3) * 64 + (l & 7)) * 128;
        #pragma unroll
        for (int dt = 0; dt < 2; ++dt) {
            float4_t o = acc[dt][qt] * inv[qt];
            *reinterpret_cast<float4_t*>(outb + basep + dt * 16 + q * 4) = o;
        }
    }

    __syncthreads();   // O-stores visible block-wide; Vt complete since last barrier

    // ---- depthwise 3x3 conv + bias (window-local SAME pad) from LDS V, RMW out
    int c4 = (t & 7) * 4;      // relative channel 0..28
    int h  = t >> 3;           // 0..63
    float4_t outv[8];
    #pragma unroll
    for (int cc = 0; cc < 4; ++cc) {
        int c = c4 + cc;
        float w9[9];
        #pragma unroll
        for (int i = 0; i < 9; ++i) w9[i] = cw[(n * 32 + c) * 9 + i];
        float bias = cb[n * 32 + c];
        float rv[3][8];
        #pragma unroll
        for (int rr = 0; rr < 3; ++rr) {
            int hh = h - 1 + rr;
            if (hh >= 0 && hh < 64) {
                short8 u = *reinterpret_cast<const short8*>(&Vt[c * V520 + hh * 8]);
                #pragma unroll
                for (int j = 0; j < 8; ++j)
                    rv[rr][j] = bitsf(((unsigned)(unsigned short)u[j]) << 16);
            } else {
                #pragma unroll
                for (int j = 0; j < 8; ++j) rv[rr][j] = 0.f;
            }
        }
        #pragma unroll
        for (int w = 0; w < 8; ++w) {
            float o = bias;
            #pragma unroll
            for (int rr = 0; rr < 3; ++rr) {
                if (w > 0) o += rv[rr][w - 1] * w9[rr * 3 + 0];
                o += rv[rr][w] * w9[rr * 3 + 1];
                if (w < 7) o += rv[rr][w + 1] * w9[rr * 3 + 2];
            }
            outv[w][cc] = o;
        }
    }
    #pragma unroll
    for (int w = 0; w < 8; ++w) {
        size_t off = (size_t)h * 8192 + w * 128 + c4;
        float4_t cur = *reinterpret_cast<const float4_t*>(outb + off);
        cur += outv[w];
        *reinterpret_cast<float4_t*>(outb + off) = cur;
    }
}

extern "C" void kernel_launch(void* const* d_in, const int* in_sizes, int n_in,
                              void* d_out, int out_size, void* d_ws, size_t ws_size,
                              hipStream_t stream) {
    const float* temp = (const float*)d_in[0];
    const float* cw   = (const float*)d_in[1];
    const float* cb   = (const float*)d_in[2];
    float* out = (float*)d_out;
    hipLaunchKernelGGL(cswin_fused, dim3(512), dim3(512), 0, stream, temp, cw, cb, out);
}

// Round 3
// 181.378 us; speedup vs baseline: 1.0581x; 1.0536x over previous
//
#include <hip/hip_runtime.h>

typedef __attribute__((ext_vector_type(8))) short short8;
typedef __attribute__((ext_vector_type(4))) float float4_t;
typedef __attribute__((ext_vector_type(4))) int int4_t;
typedef __attribute__((ext_vector_type(2))) unsigned uint2_t;

#define CH_STRIDE 4096        // 64*64 spatial per channel
#define IMG_STRIDE 524288     // 128 channels * 4096
#define HW 4096
#define V520 520              // Vt row stride (shorts); 1040B rows keep 16B align

// float -> bf16 bits, round-to-nearest-even (finite inputs only)
static __device__ __forceinline__ short f2b(float x) {
    unsigned u = __builtin_bit_cast(unsigned, x);
    u = (u + 0x7fffu + ((u >> 16) & 1u)) >> 16;
    return (short)u;
}
static __device__ __forceinline__ float bitsf(unsigned u) { return __builtin_bit_cast(float, u); }
static __device__ __forceinline__ unsigned bitsu(float f) { return __builtin_bit_cast(unsigned, f); }

// Fused CSWin block: flash attention (S^T = K*Q^T, permlane P-exchange,
// O^T = V^T*P^T) + depthwise 3x3 conv rpe from LDS-resident V, one launch.
// Grid 512 = (nw, b, head), nw in high bits for XCD L2 locality.
//
// R3 change: P-exchange rewritten from 8x ds_bpermute (__shfl) + 4x cndmask
// per (qt,g) to 4x v_permlane{32,16}_swap_b32 (gfx950 VALU cross-lane).
// Rationale (R2 post-mortem): removing a barrier + fully hiding global loads
// changed nothing -> critical path is the in-loop S->exp2->exchange->PV chain.
// The 512 bpermutes/wave were both the largest LDS-pipe consumer (~2K cyc/wave
// issue) and the longest latency link (~120cy + lgkmcnt drain each use).
// permlane route: swap32(pa,pb) -> swap16(r1,r2) yields BOTH even words
// (and odd words from pa1/pb1), ~4cy VALU latency, no LDS traffic, no waitcnt.
// Mapping verified by element-chase (dest lane 17 w0 <- pa0[33]; lane 33 w0
// <- pb0[1]; lane 17 w2 <- pa0[49]).
// NOTE: plain __launch_bounds__(512) — no min-waves arg (R1: an 85-reg cap
// rounds to the 128 VGPR HW granule, buys 0 occupancy, forces spills).
__global__ __launch_bounds__(512) void cswin_fused(
    const float* __restrict__ temp, const float* __restrict__ cw,
    const float* __restrict__ cb, float* __restrict__ out)
{
    __shared__ short Kc[2][64 * 40];   // [buf][key][d] pad-40, double-buffered
    __shared__ short Vt[32 * V520];    // [d][l] full 512-key window, persistent

    int bx = blockIdx.x;
    int nw = bx >> 6;          // window column 0..7
    int r  = bx & 63;
    int b  = r >> 2;           // batch 0..15
    int n  = r & 3;            // head 0..3

    int t    = threadIdx.x;
    int wv   = t >> 6;         // wave 0..7
    int lane = t & 63;
    int mr   = lane & 15;
    int q    = lane >> 4;

    const float* tq = temp + (size_t)b * 3 * IMG_STRIDE + (size_t)(n * 32) * CH_STRIDE + nw * 8;
    const float* tk = tq + IMG_STRIDE;
    const float* tv = tk + IMG_STRIDE;

    int row0 = wv * 64;        // this wave's 64 q-rows
    const float qscale = 0.2550348889072310f;   // (1/sqrt(32)) * log2(e)

    // Q fragments (B-operand): lane holds Q[row0+qt*16+mr][q*8+j] * qscale
    short8 Qf[4];
    #pragma unroll
    for (int qt = 0; qt < 4; ++qt) {
        int l = row0 + qt * 16 + mr;
        int sp = (l >> 3) * 64 + (l & 7);
        short8 f;
        #pragma unroll
        for (int j = 0; j < 8; ++j)
            f[j] = f2b(tq[(q * 8 + j) * CH_STRIDE + sp] * qscale);
        Qf[qt] = f;
    }

    float4_t zero4 = {0.f, 0.f, 0.f, 0.f};
    float4_t acc[2][4];
    #pragma unroll
    for (int dt = 0; dt < 2; ++dt)
        #pragma unroll
        for (int qt = 0; qt < 4; ++qt)
            acc[dt][qt] = zero4;
    float lsum[4] = {0.f, 0.f, 0.f, 0.f};

    // loader mapping: 512 threads = 32 d x 16 key-slots; thread (ld,seg)
    // handles keys seg+16i (i=0..3) -> low-conflict b16 Kc stores.
    int ld  = t >> 4;          // channel d 0..31
    int seg = t & 15;
    const float* tkld = tk + (size_t)ld * CH_STRIDE;
    const float* tvld = tv + (size_t)ld * CH_STRIDE;

    float kx[4], vx[4];
    #pragma unroll
    for (int i = 0; i < 4; ++i) {      // prefetch chunk 0
        int lb = seg + 16 * i;
        int sp = (lb >> 3) * 64 + (lb & 7);
        kx[i] = tkld[sp]; vx[i] = tvld[sp];
    }
    {   // prologue: stage chunk 0 into Kc[0] / Vt[0..63]
        #pragma unroll
        for (int i = 0; i < 4; ++i) {
            int kl = seg + 16 * i;
            Kc[0][kl * 40 + ld] = f2b(kx[i]);
            Vt[ld * V520 + kl]  = f2b(vx[i]);
        }
    }

    for (int ch = 0; ch < 8; ++ch) {
        if (ch < 7) {          // issue next chunk's loads before the barrier
            #pragma unroll
            for (int i = 0; i < 4; ++i) {
                int lb = (ch + 1) * 64 + seg + 16 * i;
                int sp = (lb >> 3) * 64 + (lb & 7);
                kx[i] = tkld[sp]; vx[i] = tvld[sp];
            }
        }
        __syncthreads();       // publishes chunk ch's Kc/Vt writes
        const short* Kr = Kc[ch & 1];

        #pragma unroll
        for (int g = 0; g < 2; ++g) {
            // S^T tiles: D[m=key][n=qrow], keys g*32..g*32+31 (local to chunk)
            short8 KaA = *reinterpret_cast<const short8*>(&Kr[((2 * g) * 16 + mr) * 40 + q * 8]);
            short8 KaB = *reinterpret_cast<const short8*>(&Kr[((2 * g + 1) * 16 + mr) * 40 + q * 8]);
            unsigned pa0[4], pa1[4], pb0[4], pb1[4];
            #pragma unroll
            for (int qt = 0; qt < 4; ++qt) {
                float4_t sA = __builtin_amdgcn_mfma_f32_16x16x32_bf16(KaA, Qf[qt], zero4, 0, 0, 0);
                float4_t sB = __builtin_amdgcn_mfma_f32_16x16x32_bf16(KaB, Qf[qt], zero4, 0, 0, 0);
                float eA0 = __builtin_amdgcn_exp2f(sA.x), eA1 = __builtin_amdgcn_exp2f(sA.y);
                float eA2 = __builtin_amdgcn_exp2f(sA.z), eA3 = __builtin_amdgcn_exp2f(sA.w);
                float eB0 = __builtin_amdgcn_exp2f(sB.x), eB1 = __builtin_amdgcn_exp2f(sB.y);
                float eB2 = __builtin_amdgcn_exp2f(sB.z), eB3 = __builtin_amdgcn_exp2f(sB.w);
                lsum[qt] += ((eA0 + eA1) + (eA2 + eA3)) + ((eB0 + eB1) + (eB2 + eB3));
                // pack pairs (truncation) with one v_perm each: [lo16=e_even, hi16=e_odd]
                pa0[qt] = __builtin_amdgcn_perm(bitsu(eA1), bitsu(eA0), 0x07060302u);
                pa1[qt] = __builtin_amdgcn_perm(bitsu(eA3), bitsu(eA2), 0x07060302u);
                pb0[qt] = __builtin_amdgcn_perm(bitsu(eB1), bitsu(eB0), 0x07060302u);
                pb1[qt] = __builtin_amdgcn_perm(bitsu(eB3), bitsu(eB2), 0x07060302u);
            }
            // V^T A-fragments for this 32-key group
            int base = ch * 64 + g * 32 + q * 8;
            short8 Va0 = *reinterpret_cast<const short8*>(&Vt[mr * V520 + base]);
            short8 Va1 = *reinterpret_cast<const short8*>(&Vt[(16 + mr) * V520 + base]);
            #pragma unroll
            for (int qt = 0; qt < 4; ++qt) {
                // C-layout P (keys q*4+r) -> B-operand (keys q*8+j) in-register:
                // word w of dest lane (q,mr) comes from lane (q&1)*32+(w>>1)*16+mr
                // of pa (q<2) / pb (q>=2). Two swap stages produce two words each.
                uint2_t re = __builtin_amdgcn_permlane32_swap(pa0[qt], pb0[qt], 0, 0);
                uint2_t we = __builtin_amdgcn_permlane16_swap(re.x, re.y, 0, 0);   // {w0, w2}
                uint2_t ro = __builtin_amdgcn_permlane32_swap(pa1[qt], pb1[qt], 0, 0);
                uint2_t wo = __builtin_amdgcn_permlane16_swap(ro.x, ro.y, 0, 0);   // {w1, w3}
                int4_t pi = { (int)we.x, (int)wo.x, (int)we.y, (int)wo.y };
                short8 Pb = __builtin_bit_cast(short8, pi);
                acc[0][qt] = __builtin_amdgcn_mfma_f32_16x16x32_bf16(Va0, Pb, acc[0][qt], 0, 0, 0);
                acc[1][qt] = __builtin_amdgcn_mfma_f32_16x16x32_bf16(Va1, Pb, acc[1][qt], 0, 0, 0);
            }
        }

        if (ch < 7) {          // stage chunk ch+1 (loads hidden under compute)
            short* Kw = Kc[(ch + 1) & 1];
            #pragma unroll
            for (int i = 0; i < 4; ++i) {
                int kl = seg + 16 * i;
                Kw[kl * 40 + ld] = f2b(kx[i]);
                Vt[ld * V520 + (ch + 1) * 64 + kl] = f2b(vx[i]);
            }
        }
    }

    // softmax denominators: reduce across quads, invert
    float inv[4];
    #pragma unroll
    for (int qt = 0; qt < 4; ++qt) {
        float v = lsum[qt];
        v += __shfl_xor(v, 16);
        v += __shfl_xor(v, 32);
        inv[qt] = 1.0f / v;
    }

    // O store: lane holds O[qrow=row0+qt*16+mr][c = n*32 + dt*16 + q*4 + r]
    float* outb = out + (size_t)b * HW * 128 + nw * 8 * 128 + n * 32;
    #pragma unroll
    for (int qt = 0; qt < 4; ++qt) {
        int l = row0 + qt * 16 + mr;
        size_t basep = (size_t)((l >> 3) * 64 + (l & 7)) * 128;
        #pragma unroll
        for (int dt = 0; dt < 2; ++dt) {
            float4_t o = acc[dt][qt] * inv[qt];
            *reinterpret_cast<float4_t*>(outb + basep + dt * 16 + q * 4) = o;
        }
    }

    __syncthreads();   // O-stores visible block-wide; Vt complete since last barrier

    // ---- depthwise 3x3 conv + bias (window-local SAME pad) from LDS V, RMW out
    int c4 = (t & 7) * 4;      // relative channel 0..28
    int h  = t >> 3;           // 0..63
    float4_t outv[8];
    #pragma unroll
    for (int cc = 0; cc < 4; ++cc) {
        int c = c4 + cc;
        float w9[9];
        #pragma unroll
        for (int i = 0; i < 9; ++i) w9[i] = cw[(n * 32 + c) * 9 + i];
        float bias = cb[n * 32 + c];
        float rv[3][8];
        #pragma unroll
        for (int rr = 0; rr < 3; ++rr) {
            int hh = h - 1 + rr;
            if (hh >= 0 && hh < 64) {
                short8 u = *reinterpret_cast<const short8*>(&Vt[c * V520 + hh * 8]);
                #pragma unroll
                for (int j = 0; j < 8; ++j)
                    rv[rr][j] = bitsf(((unsigned)(unsigned short)u[j]) << 16);
            } else {
                #pragma unroll
                for (int j = 0; j < 8; ++j) rv[rr][j] = 0.f;
            }
        }
        #pragma unroll
        for (int w = 0; w < 8; ++w) {
            float o = bias;
            #pragma unroll
            for (int rr = 0; rr < 3; ++rr) {
                if (w > 0) o += rv[rr][w - 1] * w9[rr * 3 + 0];
                o += rv[rr][w] * w9[rr * 3 + 1];
                if (w < 7) o += rv[rr][w + 1] * w9[rr * 3 + 2];
            }
            outv[w][cc] = o;
        }
    }
    #pragma unroll
    for (int w = 0; w < 8; ++w) {
        size_t off = (size_t)h * 8192 + w * 128 + c4;
        float4_t cur = *reinterpret_cast<const float4_t*>(outb + off);
        cur += outv[w];
        *reinterpret_cast<float4_t*>(outb + off) = cur;
    }
}

extern "C" void kernel_launch(void* const* d_in, const int* in_sizes, int n_in,
                              void* d_out, int out_size, void* d_ws, size_t ws_size,
                              hipStream_t stream) {
    const float* temp = (const float*)d_in[0];
    const float* cw   = (const float*)d_in[1];
    const float* cb   = (const float*)d_in[2];
    float* out = (float*)d_out;
    hipLaunchKernelGGL(cswin_fused, dim3(512), dim3(512), 0, stream, temp, cw, cb, out);
}